// Round 1
// baseline (144.230 us; speedup 1.0000x reference)
//
#include <hip/hip_runtime.h>
#include <hip/hip_bf16.h>

#define D_ 256
#define H_ 8
#define HD_ 32
#define P_ 16
#define B_ 2
#define S_ 2048
#define MTOT (B_*S_)     // 4096
#define AUGQ 64          // q(32) + pq(16) + pad(16)
#define AUGV 48          // v(32) + pq(16)

typedef __attribute__((ext_vector_type(8))) short short8;
typedef __attribute__((ext_vector_type(4))) short short4v;
typedef __attribute__((ext_vector_type(4))) float f32x4;

static __device__ __forceinline__ short bf16_of(float f) {
  union { __hip_bfloat16 h; short s; } u;
  u.h = __float2bfloat16(f);
  return u.s;
}
static __device__ __forceinline__ float f_of_bf16(short s) {
  union { __hip_bfloat16 h; short s; } u;
  u.s = s;
  return __bfloat162float(u.h);
}

// ---------------- prep kernels ----------------

__global__ void prep_weights(const float* __restrict__ Wq, const float* __restrict__ Wk,
                             const float* __restrict__ Wv, const float* __restrict__ Wo,
                             short* __restrict__ Wqkv_t, short* __restrict__ Wo_t) {
  int i = blockIdx.x * 256 + threadIdx.x;
  int stride = gridDim.x * 256;
  for (int idx = i; idx < 768 * 256; idx += stride) {
    int n = idx >> 8, k = idx & 255;
    const float* W = (n < 256) ? Wq : (n < 512 ? Wk : Wv);
    int nn = n & 255;
    Wqkv_t[idx] = bf16_of(W[k * 256 + nn]);
  }
  for (int idx = i; idx < 256 * 256; idx += stride) {
    int n = idx >> 8, k = idx & 255;
    Wo_t[idx] = bf16_of(Wo[k * 256 + n]);
  }
}

__global__ void prep_x(const float* __restrict__ X, short* __restrict__ Xb) {
  int i = blockIdx.x * 256 + threadIdx.x;   // one per 4 floats
  if (i < MTOT * D_ / 4) {
    float4 v = reinterpret_cast<const float4*>(X)[i];
    short4v o;
    o[0] = bf16_of(v.x); o[1] = bf16_of(v.y); o[2] = bf16_of(v.z); o[3] = bf16_of(v.w);
    reinterpret_cast<short4v*>(Xb)[i] = o;
  }
}

// pq/pk (K=3) into augmented slots + zero pads
__global__ void prep_pq(const float* __restrict__ coords,
                        const float* __restrict__ Wpq, const float* __restrict__ bpq,
                        const float* __restrict__ Wpk, const float* __restrict__ bpk,
                        short* __restrict__ Qa, short* __restrict__ Ka, short* __restrict__ Va) {
  int gid = blockIdx.x * 256 + threadIdx.x;  // MTOT*128
  if (gid >= MTOT * 128) return;
  int m = gid >> 7;       // b*S+s
  int j = gid & 127;      // h*16+p
  int h = j >> 4, p = j & 15;
  int b = m >> 11, s = m & (S_ - 1);
  float r0 = coords[m * 9 + 3 + 0];  // coords[b,s,1,:]
  float r1 = coords[m * 9 + 3 + 1];
  float r2 = coords[m * 9 + 3 + 2];
  float pq = r0 * Wpq[0 * 128 + j] + r1 * Wpq[1 * 128 + j] + r2 * Wpq[2 * 128 + j] + bpq[j];
  float pk = r0 * Wpk[0 * 128 + j] + r1 * Wpk[1 * 128 + j] + r2 * Wpk[2 * 128 + j] + bpk[j];
  size_t base = ((size_t)(b * H_ + h) * S_ + s);
  Qa[base * AUGQ + 32 + p] = bf16_of(pq);
  Qa[base * AUGQ + 48 + p] = 0;
  Ka[base * AUGQ + 32 + p] = bf16_of(pk * 0.25f);
  Ka[base * AUGQ + 48 + p] = 0;
  Va[base * AUGV + 32 + p] = bf16_of(pq);
}

// ---------------- QKV GEMM (M=4096, N=768, K=256) ----------------

__global__ __launch_bounds__(256) void qkv_gemm(
    const short* __restrict__ Xb, const short* __restrict__ Wt,
    const float* __restrict__ bq, const float* __restrict__ bk, const float* __restrict__ bv,
    short* __restrict__ Qa, short* __restrict__ Ka, short* __restrict__ Va) {
  __shared__ __align__(16) short As[64 * 72];
  __shared__ __align__(16) short Bs[64 * 72];
  int m0 = blockIdx.x * 64;
  int n0 = blockIdx.y * 64;
  int tid = threadIdx.x;
  int lane = tid & 63, w = tid >> 6;
  int wr = (w >> 1) * 32, wc = (w & 1) * 32;
  f32x4 acc[2][2] = {};
  int kf = (lane >> 4) * 8;
  for (int k0 = 0; k0 < 256; k0 += 32) {
    __syncthreads();
    {
      int row = tid >> 2, ko = (tid & 3) * 8;
      *reinterpret_cast<uint4*>(&As[row * 72 + ko]) =
          *reinterpret_cast<const uint4*>(&Xb[(m0 + row) * 256 + k0 + ko]);
      *reinterpret_cast<uint4*>(&Bs[row * 72 + ko]) =
          *reinterpret_cast<const uint4*>(&Wt[(n0 + row) * 256 + k0 + ko]);
    }
    __syncthreads();
    short8 a[2], bb[2];
#pragma unroll
    for (int i = 0; i < 2; i++)
      a[i] = *reinterpret_cast<const short8*>(&As[(wr + i * 16 + (lane & 15)) * 72 + kf]);
#pragma unroll
    for (int j = 0; j < 2; j++)
      bb[j] = *reinterpret_cast<const short8*>(&Bs[(wc + j * 16 + (lane & 15)) * 72 + kf]);
#pragma unroll
    for (int i = 0; i < 2; i++)
#pragma unroll
      for (int j = 0; j < 2; j++)
        acc[i][j] = __builtin_amdgcn_mfma_f32_16x16x32_bf16(a[i], bb[j], acc[i][j], 0, 0, 0);
  }
  const float scale = 0.17677669529663687f;  // 1/sqrt(32)
#pragma unroll
  for (int i = 0; i < 2; i++)
#pragma unroll
    for (int j = 0; j < 2; j++)
#pragma unroll
      for (int r = 0; r < 4; r++) {
        int row = m0 + wr + i * 16 + (lane >> 4) * 4 + r;
        int n = n0 + wc + j * 16 + (lane & 15);
        float v = acc[i][j][r];
        int b = row >> 11, s = row & (S_ - 1);
        if (n < 256) {
          v = (v + bq[n]) * scale;
          int h = n >> 5, d = n & 31;
          Qa[((size_t)(b * H_ + h) * S_ + s) * AUGQ + d] = bf16_of(v);
        } else if (n < 512) {
          int nn = n - 256;
          v += bk[nn];
          int h = nn >> 5, d = nn & 31;
          Ka[((size_t)(b * H_ + h) * S_ + s) * AUGQ + d] = bf16_of(v);
        } else {
          int nn = n - 512;
          v += bv[nn];
          int h = nn >> 5, d = nn & 31;
          Va[((size_t)(b * H_ + h) * S_ + s) * AUGV + d] = bf16_of(v);
        }
      }
}

// ---------------- flash attention ----------------
// grid: (S/64, H, B); block 256 = 4 waves, each wave owns 16 queries.

__global__ __launch_bounds__(256) void attn(
    const short* __restrict__ Qa, const short* __restrict__ Ka, const short* __restrict__ Va,
    const int* __restrict__ mask, short* __restrict__ ctx_seq, short* __restrict__ ctx_pt) {
  __shared__ __align__(16) short Kas[64 * 72];
  __shared__ __align__(16) short VasT[48 * 72];
  __shared__ __align__(16) short Pl[4][16 * 72];
  __shared__ float msk[64];
  int it = blockIdx.x;
  int h = blockIdx.y;
  int b = blockIdx.z;
  int tid = threadIdx.x, lane = tid & 63, w = tid >> 6;
  int q0 = it * 64 + w * 16;
  size_t bh = (size_t)(b * H_ + h) * S_;
  int kf = (lane >> 4) * 8;

  short8 aq[2];
#pragma unroll
  for (int c = 0; c < 2; c++)
    aq[c] = *reinterpret_cast<const short8*>(&Qa[(bh + q0 + (lane & 15)) * AUGQ + c * 32 + kf]);

  f32x4 Oacc[3] = {};
  float mrow[4], lrow[4];
#pragma unroll
  for (int r = 0; r < 4; r++) { mrow[r] = -3e38f; lrow[r] = 0.f; }

  for (int jt = 0; jt < S_ / 64; jt++) {
    __syncthreads();
    // stage K-aug tile [64 keys][64 feats]
    for (int c = tid; c < 512; c += 256) {
      int row = c >> 3, ko = (c & 7) * 8;
      *reinterpret_cast<uint4*>(&Kas[row * 72 + ko]) =
          *reinterpret_cast<const uint4*>(&Ka[(bh + jt * 64 + row) * AUGQ + ko]);
    }
    // stage V-aug tile transposed: VasT[n][key]
    for (int c = tid; c < 384; c += 256) {
      int row = c / 6, no = (c % 6) * 8;
      short8 v = *reinterpret_cast<const short8*>(&Va[(bh + jt * 64 + row) * AUGV + no]);
#pragma unroll
      for (int j2 = 0; j2 < 8; j2++) VasT[(no + j2) * 72 + row] = v[j2];
    }
    if (tid < 64) msk[tid] = mask[b * S_ + jt * 64 + tid] ? 0.f : -1e9f;
    __syncthreads();

    // scores: 4 sub-tiles of 16 keys
    f32x4 sc[4];
#pragma unroll
    for (int sub = 0; sub < 4; sub++) {
      short8 bk0 = *reinterpret_cast<const short8*>(&Kas[(sub * 16 + (lane & 15)) * 72 + 0 + kf]);
      short8 bk1 = *reinterpret_cast<const short8*>(&Kas[(sub * 16 + (lane & 15)) * 72 + 32 + kf]);
      f32x4 s0 = {};
      s0 = __builtin_amdgcn_mfma_f32_16x16x32_bf16(aq[0], bk0, s0, 0, 0, 0);
      s0 = __builtin_amdgcn_mfma_f32_16x16x32_bf16(aq[1], bk1, s0, 0, 0, 0);
      float mk = msk[sub * 16 + (lane & 15)];
#pragma unroll
      for (int r = 0; r < 4; r++) s0[r] += mk;
      sc[sub] = s0;
    }

    // online softmax (rows replicated across 16-lane groups)
    float alpha[4];
#pragma unroll
    for (int r = 0; r < 4; r++) {
      float mx = fmaxf(fmaxf(sc[0][r], sc[1][r]), fmaxf(sc[2][r], sc[3][r]));
      mx = fmaxf(mx, __shfl_xor(mx, 1));
      mx = fmaxf(mx, __shfl_xor(mx, 2));
      mx = fmaxf(mx, __shfl_xor(mx, 4));
      mx = fmaxf(mx, __shfl_xor(mx, 8));
      float mnew = fmaxf(mrow[r], mx);
      alpha[r] = __expf(mrow[r] - mnew);
      mrow[r] = mnew;
      float rs = 0.f;
#pragma unroll
      for (int sub = 0; sub < 4; sub++) {
        float p = __expf(sc[sub][r] - mnew);
        sc[sub][r] = p;
        rs += p;
      }
      rs += __shfl_xor(rs, 1); rs += __shfl_xor(rs, 2);
      rs += __shfl_xor(rs, 4); rs += __shfl_xor(rs, 8);
      lrow[r] = lrow[r] * alpha[r] + rs;
    }
#pragma unroll
    for (int t = 0; t < 3; t++)
#pragma unroll
      for (int r = 0; r < 4; r++) Oacc[t][r] *= alpha[r];

    // P -> LDS (bf16), per-wave region, then read as A-fragments
#pragma unroll
    for (int sub = 0; sub < 4; sub++)
#pragma unroll
      for (int r = 0; r < 4; r++)
        Pl[w][((lane >> 4) * 4 + r) * 72 + sub * 16 + (lane & 15)] = bf16_of(sc[sub][r]);

    short8 pa[2];
#pragma unroll
    for (int kc = 0; kc < 2; kc++)
      pa[kc] = *reinterpret_cast<const short8*>(&Pl[w][(lane & 15) * 72 + kc * 32 + kf]);
#pragma unroll
    for (int t = 0; t < 3; t++) {
#pragma unroll
      for (int kc = 0; kc < 2; kc++) {
        short8 vb = *reinterpret_cast<const short8*>(&VasT[(t * 16 + (lane & 15)) * 72 + kc * 32 + kf]);
        Oacc[t] = __builtin_amdgcn_mfma_f32_16x16x32_bf16(pa[kc], vb, Oacc[t], 0, 0, 0);
      }
    }
  }

  // epilogue
#pragma unroll
  for (int t = 0; t < 3; t++)
#pragma unroll
    for (int r = 0; r < 4; r++) {
      int q = q0 + (lane >> 4) * 4 + r;
      int n = t * 16 + (lane & 15);
      float v = Oacc[t][r] / lrow[r];
      int m = b * S_ + q;
      if (n < 32) ctx_seq[(size_t)m * 256 + h * 32 + n] = bf16_of(v);
      else        ctx_pt[(size_t)m * 128 + h * 16 + (n - 32)] = bf16_of(v);
    }
}

// ---------------- output projection (M=4096, N=256, K=256) ----------------

__global__ __launch_bounds__(256) void out_gemm(
    const short* __restrict__ Ctx, const short* __restrict__ Wot,
    const float* __restrict__ bo, float* __restrict__ Out) {
  __shared__ __align__(16) short As[64 * 72];
  __shared__ __align__(16) short Bs[64 * 72];
  int m0 = blockIdx.x * 64;
  int n0 = blockIdx.y * 64;
  int tid = threadIdx.x;
  int lane = tid & 63, w = tid >> 6;
  int wr = (w >> 1) * 32, wc = (w & 1) * 32;
  f32x4 acc[2][2] = {};
  int kf = (lane >> 4) * 8;
  for (int k0 = 0; k0 < 256; k0 += 32) {
    __syncthreads();
    {
      int row = tid >> 2, ko = (tid & 3) * 8;
      *reinterpret_cast<uint4*>(&As[row * 72 + ko]) =
          *reinterpret_cast<const uint4*>(&Ctx[(m0 + row) * 256 + k0 + ko]);
      *reinterpret_cast<uint4*>(&Bs[row * 72 + ko]) =
          *reinterpret_cast<const uint4*>(&Wot[(n0 + row) * 256 + k0 + ko]);
    }
    __syncthreads();
    short8 a[2], bb[2];
#pragma unroll
    for (int i = 0; i < 2; i++)
      a[i] = *reinterpret_cast<const short8*>(&As[(wr + i * 16 + (lane & 15)) * 72 + kf]);
#pragma unroll
    for (int j = 0; j < 2; j++)
      bb[j] = *reinterpret_cast<const short8*>(&Bs[(wc + j * 16 + (lane & 15)) * 72 + kf]);
#pragma unroll
    for (int i = 0; i < 2; i++)
#pragma unroll
      for (int j = 0; j < 2; j++)
        acc[i][j] = __builtin_amdgcn_mfma_f32_16x16x32_bf16(a[i], bb[j], acc[i][j], 0, 0, 0);
  }
#pragma unroll
  for (int i = 0; i < 2; i++)
#pragma unroll
    for (int j = 0; j < 2; j++)
#pragma unroll
      for (int r = 0; r < 4; r++) {
        int row = m0 + wr + i * 16 + (lane >> 4) * 4 + r;
        int n = n0 + wc + j * 16 + (lane & 15);
        Out[(size_t)row * 256 + n] = acc[i][j][r] + bo[n];
      }
}

// ---------------- point projection (tiny) ----------------

__global__ void point_proj(const short* __restrict__ ctx_pt, const float* __restrict__ Wpo,
                           const float* __restrict__ bpo, float* __restrict__ out) {
  int m = blockIdx.x * 256 + threadIdx.x;
  if (m >= MTOT) return;
  float a0 = 0.f, a1 = 0.f, a2 = 0.f;
  for (int j = 0; j < 128; j++) {
    float v = f_of_bf16(ctx_pt[m * 128 + j]);
    a0 += v * Wpo[j * 3 + 0];
    a1 += v * Wpo[j * 3 + 1];
    a2 += v * Wpo[j * 3 + 2];
  }
  out[m * 3 + 0] = a0 + bpo[0];
  out[m * 3 + 1] = a1 + bpo[1];
  out[m * 3 + 2] = a2 + bpo[2];
}

// ---------------- launch ----------------

extern "C" void kernel_launch(void* const* d_in, const int* in_sizes, int n_in,
                              void* d_out, int out_size, void* d_ws, size_t ws_size,
                              hipStream_t stream) {
  const float* seq    = (const float*)d_in[0];
  const float* coords = (const float*)d_in[1];
  const int*   mask   = (const int*)d_in[3];
  const float* Wq  = (const float*)d_in[4];
  const float* bq  = (const float*)d_in[5];
  const float* Wk  = (const float*)d_in[6];
  const float* bk  = (const float*)d_in[7];
  const float* Wv  = (const float*)d_in[8];
  const float* bv  = (const float*)d_in[9];
  const float* Wpq = (const float*)d_in[10];
  const float* bpq = (const float*)d_in[11];
  const float* Wpk = (const float*)d_in[12];
  const float* bpk = (const float*)d_in[13];
  const float* Wo  = (const float*)d_in[14];
  const float* bo  = (const float*)d_in[15];
  const float* Wpo = (const float*)d_in[16];
  const float* bpo = (const float*)d_in[17];
  float* out = (float*)d_out;

  char* ws = (char*)d_ws;
  short* Xb     = (short*)ws; ws += (size_t)MTOT * D_ * 2;           // 2 MB
  short* Wqkv_t = (short*)ws; ws += 768 * 256 * 2;                   // 384 KB
  short* Wo_t   = (short*)ws; ws += 256 * 256 * 2;                   // 128 KB
  short* Qa     = (short*)ws; ws += (size_t)B_ * H_ * S_ * AUGQ * 2; // 4 MB
  short* Ka     = (short*)ws; ws += (size_t)B_ * H_ * S_ * AUGQ * 2; // 4 MB
  short* Va     = (short*)ws; ws += (size_t)B_ * H_ * S_ * AUGV * 2; // 3 MB
  short* ctx_seq= (short*)ws; ws += (size_t)MTOT * D_ * 2;           // 2 MB
  short* ctx_pt = (short*)ws; ws += (size_t)MTOT * 128 * 2;          // 1 MB

  prep_weights<<<256, 256, 0, stream>>>(Wq, Wk, Wv, Wo, Wqkv_t, Wo_t);
  prep_x<<<(MTOT * D_ / 4 + 255) / 256, 256, 0, stream>>>(seq, Xb);
  prep_pq<<<(MTOT * 128 + 255) / 256, 256, 0, stream>>>(coords, Wpq, bpq, Wpk, bpk, Qa, Ka, Va);
  qkv_gemm<<<dim3(MTOT / 64, 768 / 64), 256, 0, stream>>>(Xb, Wqkv_t, bq, bk, bv, Qa, Ka, Va);
  attn<<<dim3(S_ / 64, H_, B_), 256, 0, stream>>>(Qa, Ka, Va, mask, ctx_seq, ctx_pt);
  out_gemm<<<dim3(MTOT / 64, 256 / 64), 256, 0, stream>>>(ctx_seq, Wo_t, bo, out);
  point_proj<<<(MTOT + 255) / 256, 256, 0, stream>>>(ctx_pt, Wpo, bpo, out + (size_t)MTOT * D_);
}

// Round 2
// 82.656 us; speedup vs baseline: 1.7449x; 1.7449x over previous
//
#include <hip/hip_runtime.h>
#include <hip/hip_bf16.h>

#define D_ 256
#define H_ 8
#define HD_ 32
#define P_ 16
#define B_ 2
#define S_ 2048
#define MTOT (B_*S_)     // 4096
#define AUGQ 64          // q(32) + pq(16) + pad(16)
#define AUGV 48          // v(32) + pq(16)
#define NBH 16           // B_*H_

typedef __attribute__((ext_vector_type(8))) short short8;
typedef __attribute__((ext_vector_type(4))) short short4v;
typedef __attribute__((ext_vector_type(4))) float f32x4;

static __device__ __forceinline__ short bf16_of(float f) {
  union { __hip_bfloat16 h; short s; } u;
  u.h = __float2bfloat16(f);
  return u.s;
}
static __device__ __forceinline__ float f_of_bf16(short s) {
  union { __hip_bfloat16 h; short s; } u;
  u.s = s;
  return __bfloat162float(u.h);
}

// ---------------- prep kernels ----------------

__global__ void prep_weights(const float* __restrict__ Wq, const float* __restrict__ Wk,
                             const float* __restrict__ Wv, const float* __restrict__ Wo,
                             short* __restrict__ Wqkv_t, short* __restrict__ Wo_t) {
  int i = blockIdx.x * 256 + threadIdx.x;
  int stride = gridDim.x * 256;
  for (int idx = i; idx < 768 * 256; idx += stride) {
    int n = idx >> 8, k = idx & 255;
    const float* W = (n < 256) ? Wq : (n < 512 ? Wk : Wv);
    int nn = n & 255;
    Wqkv_t[idx] = bf16_of(W[k * 256 + nn]);
  }
  for (int idx = i; idx < 256 * 256; idx += stride) {
    int n = idx >> 8, k = idx & 255;
    Wo_t[idx] = bf16_of(Wo[k * 256 + n]);
  }
}

__global__ void prep_x(const float* __restrict__ X, short* __restrict__ Xb) {
  int i = blockIdx.x * 256 + threadIdx.x;
  if (i < MTOT * D_ / 4) {
    float4 v = reinterpret_cast<const float4*>(X)[i];
    short4v o;
    o[0] = bf16_of(v.x); o[1] = bf16_of(v.y); o[2] = bf16_of(v.z); o[3] = bf16_of(v.w);
    reinterpret_cast<short4v*>(Xb)[i] = o;
  }
}

// pq/pk (K=3) into augmented slots + zero pads (Va row-major; transposed later)
__global__ void prep_pq(const float* __restrict__ coords,
                        const float* __restrict__ Wpq, const float* __restrict__ bpq,
                        const float* __restrict__ Wpk, const float* __restrict__ bpk,
                        short* __restrict__ Qa, short* __restrict__ Ka, short* __restrict__ Va) {
  int gid = blockIdx.x * 256 + threadIdx.x;  // MTOT*128
  if (gid >= MTOT * 128) return;
  int m = gid >> 7;       // b*S+s
  int j = gid & 127;      // h*16+p
  int h = j >> 4, p = j & 15;
  int b = m >> 11, s = m & (S_ - 1);
  float r0 = coords[m * 9 + 3 + 0];
  float r1 = coords[m * 9 + 3 + 1];
  float r2 = coords[m * 9 + 3 + 2];
  float pq = r0 * Wpq[0 * 128 + j] + r1 * Wpq[1 * 128 + j] + r2 * Wpq[2 * 128 + j] + bpq[j];
  float pk = r0 * Wpk[0 * 128 + j] + r1 * Wpk[1 * 128 + j] + r2 * Wpk[2 * 128 + j] + bpk[j];
  size_t base = ((size_t)(b * H_ + h) * S_ + s);
  Qa[base * AUGQ + 32 + p] = bf16_of(pq);
  Qa[base * AUGQ + 48 + p] = 0;
  Ka[base * AUGQ + 32 + p] = bf16_of(pk * 0.25f);
  Ka[base * AUGQ + 48 + p] = 0;
  Va[base * AUGV + 32 + p] = bf16_of(pq);
}

// ---------------- V transpose: Va[bh][s][48] -> VaT[bh][48][S] ----------------

__global__ __launch_bounds__(256) void transpose_v(const short* __restrict__ Va,
                                                   short* __restrict__ VaT) {
  __shared__ unsigned int tile[64][25];  // [s][dword-pair], pad -> conflict-free
  int bh = blockIdx.y;
  int s0 = blockIdx.x * 64;
  int tid = threadIdx.x;
  for (int u = tid; u < 384; u += 256) {
    int row = u / 6, c = u % 6;
    uint4 v = *reinterpret_cast<const uint4*>(&Va[((size_t)bh * S_ + s0 + row) * 48 + c * 8]);
    tile[row][c * 4 + 0] = v.x; tile[row][c * 4 + 1] = v.y;
    tile[row][c * 4 + 2] = v.z; tile[row][c * 4 + 3] = v.w;
  }
  __syncthreads();
  int lane = tid & 63, wv = tid >> 6;
  for (int dp = wv * 6; dp < wv * 6 + 6; dp++) {
    unsigned int v = tile[lane][dp];
    size_t base = ((size_t)bh * 48 + dp * 2) * S_ + s0 + lane;
    VaT[base] = (short)(v & 0xffff);
    VaT[base + S_] = (short)(v >> 16);
  }
}

// ---------------- QKV GEMM (M=4096, N=768, K=256) ----------------

__global__ __launch_bounds__(256) void qkv_gemm(
    const short* __restrict__ Xb, const short* __restrict__ Wt,
    const float* __restrict__ bq, const float* __restrict__ bk, const float* __restrict__ bv,
    short* __restrict__ Qa, short* __restrict__ Ka, short* __restrict__ Va) {
  __shared__ __align__(16) short As[64 * 72];
  __shared__ __align__(16) short Bs[64 * 72];
  int m0 = blockIdx.x * 64;
  int n0 = blockIdx.y * 64;
  int tid = threadIdx.x;
  int lane = tid & 63, w = tid >> 6;
  int wr = (w >> 1) * 32, wc = (w & 1) * 32;
  f32x4 acc[2][2] = {};
  int kf = (lane >> 4) * 8;
  for (int k0 = 0; k0 < 256; k0 += 32) {
    __syncthreads();
    {
      int row = tid >> 2, ko = (tid & 3) * 8;
      *reinterpret_cast<uint4*>(&As[row * 72 + ko]) =
          *reinterpret_cast<const uint4*>(&Xb[(m0 + row) * 256 + k0 + ko]);
      *reinterpret_cast<uint4*>(&Bs[row * 72 + ko]) =
          *reinterpret_cast<const uint4*>(&Wt[(n0 + row) * 256 + k0 + ko]);
    }
    __syncthreads();
    short8 a[2], bb[2];
#pragma unroll
    for (int i = 0; i < 2; i++)
      a[i] = *reinterpret_cast<const short8*>(&As[(wr + i * 16 + (lane & 15)) * 72 + kf]);
#pragma unroll
    for (int j = 0; j < 2; j++)
      bb[j] = *reinterpret_cast<const short8*>(&Bs[(wc + j * 16 + (lane & 15)) * 72 + kf]);
#pragma unroll
    for (int i = 0; i < 2; i++)
#pragma unroll
      for (int j = 0; j < 2; j++)
        acc[i][j] = __builtin_amdgcn_mfma_f32_16x16x32_bf16(a[i], bb[j], acc[i][j], 0, 0, 0);
  }
  const float scale = 0.17677669529663687f;  // 1/sqrt(32)
#pragma unroll
  for (int i = 0; i < 2; i++)
#pragma unroll
    for (int j = 0; j < 2; j++)
#pragma unroll
      for (int r = 0; r < 4; r++) {
        int row = m0 + wr + i * 16 + (lane >> 4) * 4 + r;
        int n = n0 + wc + j * 16 + (lane & 15);
        float v = acc[i][j][r];
        int b = row >> 11, s = row & (S_ - 1);
        if (n < 256) {
          v = (v + bq[n]) * scale;
          int h = n >> 5, d = n & 31;
          Qa[((size_t)(b * H_ + h) * S_ + s) * AUGQ + d] = bf16_of(v);
        } else if (n < 512) {
          int nn = n - 256;
          v += bk[nn];
          int h = nn >> 5, d = nn & 31;
          Ka[((size_t)(b * H_ + h) * S_ + s) * AUGQ + d] = bf16_of(v);
        } else {
          int nn = n - 512;
          v += bv[nn];
          int h = nn >> 5, d = nn & 31;
          Va[((size_t)(b * H_ + h) * S_ + s) * AUGV + d] = bf16_of(v);
        }
      }
}

// ---------------- flash attention, split-K=2, no-max softmax ----------------
// grid: (S/64, H, B*2); block 256 = 4 waves, each wave owns 16 queries.

__global__ __launch_bounds__(256) void attn(
    const short* __restrict__ Qa, const short* __restrict__ Ka, const short* __restrict__ VaT,
    const int* __restrict__ mask, float* __restrict__ AccO, float* __restrict__ AccL) {
  __shared__ __align__(16) short Kas[64 * 72];
  __shared__ __align__(16) short VasT[48 * 72];
  __shared__ __align__(16) short Pl[4][16 * 72];
  __shared__ float msk[64];
  int it = blockIdx.x;
  int h = blockIdx.y;
  int bz = blockIdx.z;
  int b = bz >> 1, split = bz & 1;
  int tid = threadIdx.x, lane = tid & 63, w = tid >> 6;
  int t = lane & 15, g = lane >> 4;
  int q0 = it * 64 + w * 16;
  int bhv = b * H_ + h;
  size_t bh = (size_t)bhv * S_;
  int kf = g * 8;

  short8 aq[2];
#pragma unroll
  for (int c = 0; c < 2; c++)
    aq[c] = *reinterpret_cast<const short8*>(&Qa[(bh + q0 + t) * AUGQ + c * 32 + kf]);

  f32x4 Oacc[3] = {};
  float lsum[4] = {0.f, 0.f, 0.f, 0.f};

  // register staging
  uint4 kreg0, kreg1, vreg0, vreg1;
  float mreg = 0.f;
  int srow = tid >> 3, sko = (tid & 7) * 8;

  auto issue = [&](int jt) {
    // K tile: 64 rows x 64 shorts, contiguous 8KB
    const uint4* ksrc = reinterpret_cast<const uint4*>(&Ka[(bh + jt * 64) * AUGQ]);
    kreg0 = ksrc[tid];
    kreg1 = ksrc[tid + 256];
    // VT tile: 48 rows (features) x 64 keys, row stride S
    size_t vbase = (size_t)bhv * 48 * S_ + jt * 64;
    vreg0 = *reinterpret_cast<const uint4*>(&VaT[vbase + (size_t)srow * S_ + sko]);
    if (tid < 128)
      vreg1 = *reinterpret_cast<const uint4*>(&VaT[vbase + (size_t)(srow + 32) * S_ + sko]);
    if (tid < 64) mreg = mask[b * S_ + jt * 64 + tid] ? 0.f : -1e9f;
  };

  int jt0 = split * (S_ / 128);
  issue(jt0);

  for (int j = 0; j < S_ / 128; j++) {
    int jt = jt0 + j;
    __syncthreads();
    // write LDS from regs
    *reinterpret_cast<uint4*>(&Kas[srow * 72 + sko]) = kreg0;
    *reinterpret_cast<uint4*>(&Kas[(srow + 32) * 72 + sko]) = kreg1;
    *reinterpret_cast<uint4*>(&VasT[srow * 72 + sko]) = vreg0;
    if (tid < 128)
      *reinterpret_cast<uint4*>(&VasT[(srow + 32) * 72 + sko]) = vreg1;
    if (tid < 64) msk[tid] = mreg;
    __syncthreads();
    if (j + 1 < S_ / 128) issue(jt + 1);

    // scores + exp (no max subtraction) + P->LDS
#pragma unroll
    for (int sub = 0; sub < 4; sub++) {
      short8 bk0 = *reinterpret_cast<const short8*>(&Kas[(sub * 16 + t) * 72 + 0 + kf]);
      short8 bk1 = *reinterpret_cast<const short8*>(&Kas[(sub * 16 + t) * 72 + 32 + kf]);
      f32x4 s0 = {};
      s0 = __builtin_amdgcn_mfma_f32_16x16x32_bf16(aq[0], bk0, s0, 0, 0, 0);
      s0 = __builtin_amdgcn_mfma_f32_16x16x32_bf16(aq[1], bk1, s0, 0, 0, 0);
      float mk = msk[sub * 16 + t];
#pragma unroll
      for (int r = 0; r < 4; r++) {
        float p = __expf(s0[r] + mk);
        lsum[r] += p;
        Pl[w][(g * 4 + r) * 72 + sub * 16 + t] = bf16_of(p);
      }
    }

    short8 pa[2];
#pragma unroll
    for (int kc = 0; kc < 2; kc++)
      pa[kc] = *reinterpret_cast<const short8*>(&Pl[w][t * 72 + kc * 32 + kf]);
#pragma unroll
    for (int tt = 0; tt < 3; tt++) {
#pragma unroll
      for (int kc = 0; kc < 2; kc++) {
        short8 vb = *reinterpret_cast<const short8*>(&VasT[(tt * 16 + t) * 72 + kc * 32 + kf]);
        Oacc[tt] = __builtin_amdgcn_mfma_f32_16x16x32_bf16(pa[kc], vb, Oacc[tt], 0, 0, 0);
      }
    }
  }

  // reduce row sums across the 16 lanes of each group (once per kernel)
#pragma unroll
  for (int r = 0; r < 4; r++) {
    float ls = lsum[r];
    ls += __shfl_xor(ls, 1); ls += __shfl_xor(ls, 2);
    ls += __shfl_xor(ls, 4); ls += __shfl_xor(ls, 8);
    lsum[r] = ls;
  }

  // write partial accumulators (f32) + sums
  size_t obase = ((size_t)(split * NBH + bhv)) * S_;
#pragma unroll
  for (int tt = 0; tt < 3; tt++)
#pragma unroll
    for (int r = 0; r < 4; r++)
      AccO[(obase + q0 + g * 4 + r) * 48 + tt * 16 + t] = Oacc[tt][r];
  if (t == 0) {
#pragma unroll
    for (int r = 0; r < 4; r++)
      AccL[obase + q0 + g * 4 + r] = lsum[r];
  }
}

// ---------------- merge splits ----------------

__global__ __launch_bounds__(256) void merge_splits(
    const float* __restrict__ AccO, const float* __restrict__ AccL,
    short* __restrict__ ctx_seq, short* __restrict__ ctx_pt) {
  int idx = blockIdx.x * 256 + threadIdx.x;  // NBH*S*12 f32x4 chunks
  if (idx >= NBH * S_ * 12) return;
  int row = idx / 12, c4 = idx % 12;
  const f32x4* A0 = reinterpret_cast<const f32x4*>(AccO);
  const f32x4* A1 = reinterpret_cast<const f32x4*>(AccO + (size_t)NBH * S_ * 48);
  f32x4 a0 = A0[idx], a1 = A1[idx];
  float l = AccL[row] + AccL[NBH * S_ + row];
  float inv = 1.0f / l;
  short4v o;
#pragma unroll
  for (int i = 0; i < 4; i++) o[i] = bf16_of((a0[i] + a1[i]) * inv);
  int bh = row >> 11, q = row & (S_ - 1);
  int b = bh >> 3, h = bh & 7;
  size_t m = (size_t)b * S_ + q;
  if (c4 < 8)
    *reinterpret_cast<short4v*>(&ctx_seq[m * 256 + h * 32 + c4 * 4]) = o;
  else
    *reinterpret_cast<short4v*>(&ctx_pt[m * 128 + h * 16 + (c4 - 8) * 4]) = o;
}

// ---------------- output projection (M=4096, N=256, K=256) ----------------

__global__ __launch_bounds__(256) void out_gemm(
    const short* __restrict__ Ctx, const short* __restrict__ Wot,
    const float* __restrict__ bo, float* __restrict__ Out) {
  __shared__ __align__(16) short As[64 * 72];
  __shared__ __align__(16) short Bs[64 * 72];
  int m0 = blockIdx.x * 64;
  int n0 = blockIdx.y * 64;
  int tid = threadIdx.x;
  int lane = tid & 63, w = tid >> 6;
  int wr = (w >> 1) * 32, wc = (w & 1) * 32;
  f32x4 acc[2][2] = {};
  int kf = (lane >> 4) * 8;
  for (int k0 = 0; k0 < 256; k0 += 32) {
    __syncthreads();
    {
      int row = tid >> 2, ko = (tid & 3) * 8;
      *reinterpret_cast<uint4*>(&As[row * 72 + ko]) =
          *reinterpret_cast<const uint4*>(&Ctx[(m0 + row) * 256 + k0 + ko]);
      *reinterpret_cast<uint4*>(&Bs[row * 72 + ko]) =
          *reinterpret_cast<const uint4*>(&Wot[(n0 + row) * 256 + k0 + ko]);
    }
    __syncthreads();
    short8 a[2], bb[2];
#pragma unroll
    for (int i = 0; i < 2; i++)
      a[i] = *reinterpret_cast<const short8*>(&As[(wr + i * 16 + (lane & 15)) * 72 + kf]);
#pragma unroll
    for (int j = 0; j < 2; j++)
      bb[j] = *reinterpret_cast<const short8*>(&Bs[(wc + j * 16 + (lane & 15)) * 72 + kf]);
#pragma unroll
    for (int i = 0; i < 2; i++)
#pragma unroll
      for (int j = 0; j < 2; j++)
        acc[i][j] = __builtin_amdgcn_mfma_f32_16x16x32_bf16(a[i], bb[j], acc[i][j], 0, 0, 0);
  }
#pragma unroll
  for (int i = 0; i < 2; i++)
#pragma unroll
    for (int j = 0; j < 2; j++)
#pragma unroll
      for (int r = 0; r < 4; r++) {
        int row = m0 + wr + i * 16 + (lane >> 4) * 4 + r;
        int n = n0 + wc + j * 16 + (lane & 15);
        Out[(size_t)row * 256 + n] = acc[i][j][r] + bo[n];
      }
}

// ---------------- point projection (tiny) ----------------

__global__ void point_proj(const short* __restrict__ ctx_pt, const float* __restrict__ Wpo,
                           const float* __restrict__ bpo, float* __restrict__ out) {
  int m = blockIdx.x * 256 + threadIdx.x;
  if (m >= MTOT) return;
  float a0 = 0.f, a1 = 0.f, a2 = 0.f;
#pragma unroll
  for (int j8 = 0; j8 < 16; j8++) {
    short8 v = *reinterpret_cast<const short8*>(&ctx_pt[(size_t)m * 128 + j8 * 8]);
#pragma unroll
    for (int jj = 0; jj < 8; jj++) {
      float f = f_of_bf16(v[jj]);
      int j = j8 * 8 + jj;
      a0 += f * Wpo[j * 3 + 0];
      a1 += f * Wpo[j * 3 + 1];
      a2 += f * Wpo[j * 3 + 2];
    }
  }
  out[m * 3 + 0] = a0 + bpo[0];
  out[m * 3 + 1] = a1 + bpo[1];
  out[m * 3 + 2] = a2 + bpo[2];
}

// ---------------- launch ----------------

extern "C" void kernel_launch(void* const* d_in, const int* in_sizes, int n_in,
                              void* d_out, int out_size, void* d_ws, size_t ws_size,
                              hipStream_t stream) {
  const float* seq    = (const float*)d_in[0];
  const float* coords = (const float*)d_in[1];
  const int*   mask   = (const int*)d_in[3];
  const float* Wq  = (const float*)d_in[4];
  const float* bq  = (const float*)d_in[5];
  const float* Wk  = (const float*)d_in[6];
  const float* bk  = (const float*)d_in[7];
  const float* Wv  = (const float*)d_in[8];
  const float* bv  = (const float*)d_in[9];
  const float* Wpq = (const float*)d_in[10];
  const float* bpq = (const float*)d_in[11];
  const float* Wpk = (const float*)d_in[12];
  const float* bpk = (const float*)d_in[13];
  const float* Wo  = (const float*)d_in[14];
  const float* bo  = (const float*)d_in[15];
  const float* Wpo = (const float*)d_in[16];
  const float* bpo = (const float*)d_in[17];
  float* out = (float*)d_out;

  char* ws = (char*)d_ws;
  short* Xb     = (short*)ws; ws += (size_t)MTOT * D_ * 2;            // 2 MB
  short* Wqkv_t = (short*)ws; ws += 768 * 256 * 2;                    // 384 KB
  short* Wo_t   = (short*)ws; ws += 256 * 256 * 2;                    // 128 KB
  short* Qa     = (short*)ws; ws += (size_t)NBH * S_ * AUGQ * 2;      // 4 MB
  short* Ka     = (short*)ws; ws += (size_t)NBH * S_ * AUGQ * 2;      // 4 MB
  short* Va     = (short*)ws; ws += (size_t)NBH * S_ * AUGV * 2;      // 3 MB
  short* VaT    = (short*)ws; ws += (size_t)NBH * 48 * S_ * 2;        // 3 MB
  short* ctx_seq= (short*)ws; ws += (size_t)MTOT * D_ * 2;            // 2 MB
  short* ctx_pt = (short*)ws; ws += (size_t)MTOT * 128 * 2;           // 1 MB
  float* AccO   = (float*)ws; ws += (size_t)2 * NBH * S_ * 48 * 4;    // 12.6 MB
  float* AccL   = (float*)ws; ws += (size_t)2 * NBH * S_ * 4;         // 256 KB

  prep_weights<<<256, 256, 0, stream>>>(Wq, Wk, Wv, Wo, Wqkv_t, Wo_t);
  prep_x<<<(MTOT * D_ / 4 + 255) / 256, 256, 0, stream>>>(seq, Xb);
  prep_pq<<<(MTOT * 128 + 255) / 256, 256, 0, stream>>>(coords, Wpq, bpq, Wpk, bpk, Qa, Ka, Va);
  qkv_gemm<<<dim3(MTOT / 64, 768 / 64), 256, 0, stream>>>(Xb, Wqkv_t, bq, bk, bv, Qa, Ka, Va);
  transpose_v<<<dim3(S_ / 64, NBH), 256, 0, stream>>>(Va, VaT);
  attn<<<dim3(S_ / 64, H_, B_ * 2), 256, 0, stream>>>(Qa, Ka, VaT, mask, AccO, AccL);
  merge_splits<<<(NBH * S_ * 12 + 255) / 256, 256, 0, stream>>>(AccO, AccL, ctx_seq, ctx_pt);
  out_gemm<<<dim3(MTOT / 64, 256 / 64), 256, 0, stream>>>(ctx_seq, Wo_t, bo, out);
  point_proj<<<(MTOT + 255) / 256, 256, 0, stream>>>(ctx_pt, Wpo, bpo, out + (size_t)MTOT * D_);
}

// Round 4
// 70.970 us; speedup vs baseline: 2.0323x; 1.1647x over previous
//
#include <hip/hip_runtime.h>
#include <hip/hip_bf16.h>

#define D_ 256
#define H_ 8
#define B_ 2
#define S_ 2048
#define MTOT 4096
#define AUGQ 64          // q(32) + pq(16) + pad(16)
#define NBH 16           // B_*H_
#define KPAD 72
#define NJ 16            // key tiles (of 64) per split

typedef __attribute__((ext_vector_type(8))) short short8;
typedef __attribute__((ext_vector_type(4))) short short4v;
typedef __attribute__((ext_vector_type(4))) float f32x4;

static __device__ __forceinline__ short bf16_of(float f) {
  union { __hip_bfloat16 h; short s; } u;
  u.h = __float2bfloat16(f);
  return u.s;
}

static __device__ __forceinline__ f32x4 mfma16(short4v a, short4v b, f32x4 c) {
#if defined(__has_builtin) && __has_builtin(__builtin_amdgcn_mfma_f32_16x16x16bf16_1k)
  return __builtin_amdgcn_mfma_f32_16x16x16bf16_1k(a, b, c, 0, 0, 0);
#else
  asm("v_mfma_f32_16x16x16_bf16 %0, %1, %2, %0" : "+v"(c) : "v"(a), "v"(b));
  return c;
#endif
}

// ---------------- fused prep: weights cvt/transpose + pq/pk fills ----------------

__global__ void prep_all(const float* __restrict__ Wq, const float* __restrict__ Wk,
                         const float* __restrict__ Wv, const float* __restrict__ Wo,
                         const float* __restrict__ coords,
                         const float* __restrict__ Wpq, const float* __restrict__ bpq,
                         const float* __restrict__ Wpk, const float* __restrict__ bpk,
                         short* __restrict__ Wqkv_t, short* __restrict__ Wo_t,
                         short* __restrict__ Qa, short* __restrict__ Ka,
                         short* __restrict__ VaT) {
  int gid = blockIdx.x * 256 + threadIdx.x;
  int NT = gridDim.x * 256;
  for (int idx = gid; idx < 768 * 256; idx += NT) {
    int n = idx >> 8, k = idx & 255;
    const float* W = (n < 256) ? Wq : (n < 512 ? Wk : Wv);
    Wqkv_t[idx] = bf16_of(W[k * 256 + (n & 255)]);
  }
  for (int idx = gid; idx < 256 * 256; idx += NT) {
    int n = idx >> 8, k = idx & 255;
    Wo_t[idx] = bf16_of(Wo[k * 256 + n]);
  }
  for (int idx = gid; idx < MTOT * 128; idx += NT) {
    int m = idx >> 7, j = idx & 127;
    int h = j >> 4, p = j & 15;
    int b = m >> 11, s = m & 2047;
    float r0 = coords[m * 9 + 3], r1 = coords[m * 9 + 4], r2 = coords[m * 9 + 5];
    float pq = r0 * Wpq[j] + r1 * Wpq[128 + j] + r2 * Wpq[256 + j] + bpq[j];
    float pk = r0 * Wpk[j] + r1 * Wpk[128 + j] + r2 * Wpk[256 + j] + bpk[j];
    size_t base = ((size_t)(b * 8 + h) * S_ + s);
    Qa[base * AUGQ + 32 + p] = bf16_of(pq);
    Qa[base * AUGQ + 48 + p] = 0;
    Ka[base * AUGQ + 32 + p] = bf16_of(pk * 0.25f);
    Ka[base * AUGQ + 48 + p] = 0;
  }
  // pq into VaT (transposed layout [bh][32+p][s])
  for (int idx = gid; idx < NBH * 16 * (S_ / 8); idx += NT) {
    int s8 = idx & 255, p = (idx >> 8) & 15, bh = idx >> 12;
    int b = bh >> 3, h = bh & 7, j = h * 16 + p;
    float w0 = Wpq[j], w1 = Wpq[128 + j], w2 = Wpq[256 + j], bb = bpq[j];
    short8 o;
#pragma unroll
    for (int i = 0; i < 8; i++) {
      int m = b * 2048 + s8 * 8 + i;
      o[i] = bf16_of(coords[m * 9 + 3] * w0 + coords[m * 9 + 4] * w1 +
                     coords[m * 9 + 5] * w2 + bb);
    }
    *reinterpret_cast<short8*>(&VaT[((size_t)bh * 48 + 32 + p) * S_ + s8 * 8]) = o;
  }
}

// ---------------- QKV GEMM (M=4096, N=768, K=256), f32 input, vector epilogue ----------------

__global__ __launch_bounds__(256) void qkv_gemm(
    const float* __restrict__ X, const short* __restrict__ Wt,
    const float* __restrict__ bq, const float* __restrict__ bk, const float* __restrict__ bv,
    short* __restrict__ Qa, short* __restrict__ Ka, short* __restrict__ VaT) {
  __shared__ __align__(16) short As[64 * 136];
  __shared__ __align__(16) short Bs[64 * 136];
  int m0 = blockIdx.x * 64, n0 = blockIdx.y * 64;
  int tid = threadIdx.x, lane = tid & 63, w = tid >> 6;
  int t = lane & 15, g = lane >> 4, kf = g * 8;
  int wr = (w >> 1) * 32, wc = (w & 1) * 32;
  f32x4 acc[2][2] = {};
  int srow = tid >> 2, skc = (tid & 3) * 32;
  for (int ph = 0; ph < 2; ph++) {
    int k0 = ph * 128;
    __syncthreads();
    {
      const float* xs = &X[(size_t)(m0 + srow) * 256 + k0 + skc];
      short4v av[8];
#pragma unroll
      for (int i = 0; i < 8; i++) {
        f32x4 xv = *reinterpret_cast<const f32x4*>(&xs[i * 4]);
        short4v o;
        o[0] = bf16_of(xv[0]); o[1] = bf16_of(xv[1]);
        o[2] = bf16_of(xv[2]); o[3] = bf16_of(xv[3]);
        av[i] = o;
      }
#pragma unroll
      for (int i = 0; i < 8; i++)
        *reinterpret_cast<short4v*>(&As[srow * 136 + skc + i * 4]) = av[i];
      const uint4* wsrc = reinterpret_cast<const uint4*>(&Wt[(size_t)(n0 + srow) * 256 + k0 + skc]);
#pragma unroll
      for (int i = 0; i < 4; i++)
        *reinterpret_cast<uint4*>(&Bs[srow * 136 + skc + i * 8]) = wsrc[i];
    }
    __syncthreads();
#pragma unroll
    for (int kk = 0; kk < 4; kk++) {
      short8 a[2], bb[2];
#pragma unroll
      for (int i = 0; i < 2; i++)
        a[i] = *reinterpret_cast<const short8*>(&As[(wr + i * 16 + t) * 136 + kk * 32 + kf]);
#pragma unroll
      for (int jj = 0; jj < 2; jj++)
        bb[jj] = *reinterpret_cast<const short8*>(&Bs[(wc + jj * 16 + t) * 136 + kk * 32 + kf]);
#pragma unroll
      for (int i = 0; i < 2; i++)
#pragma unroll
        for (int jj = 0; jj < 2; jj++)
          acc[i][jj] = __builtin_amdgcn_mfma_f32_16x16x32_bf16(a[i], bb[jj], acc[i][jj], 0, 0, 0);
    }
  }
  // epilogue: bias/scale -> LDS bf16 tile -> vector stores
  __syncthreads();
  short* Cs = As;
  const float scale = 0.17677669529663687f;  // 1/sqrt(32)
  int b = m0 >> 11, sbase = m0 & 2047;
#pragma unroll
  for (int i = 0; i < 2; i++)
#pragma unroll
    for (int jj = 0; jj < 2; jj++)
#pragma unroll
      for (int r = 0; r < 4; r++) {
        int rl = wr + i * 16 + g * 4 + r;
        int cl = wc + jj * 16 + t;
        int n = n0 + cl;
        float v = acc[i][jj][r];
        if (n < 256) v = (v + bq[n]) * scale;
        else if (n < 512) v = v + bk[n - 256];
        else v = v + bv[n - 512];
        Cs[rl * 72 + cl] = bf16_of(v);
      }
  __syncthreads();
  if (n0 < 512) {
#pragma unroll
    for (int i2 = 0; i2 < 2; i2++) {
      int task = tid + i2 * 256;
      int row = task >> 3, c = task & 7;
      int n = n0 + c * 8;
      short* dst = (n < 256) ? Qa : Ka;
      int nn = n & 255;
      int hh = nn >> 5, d = nn & 31;
      *reinterpret_cast<short8*>(&dst[((size_t)(b * 8 + hh) * S_ + sbase + row) * AUGQ + d]) =
          *reinterpret_cast<const short8*>(&Cs[row * 72 + c * 8]);
    }
  } else {
    int hv0 = (n0 - 512) >> 5;
#pragma unroll
    for (int i2 = 0; i2 < 2; i2++) {
      int task = tid + i2 * 256;
      int fl = task >> 3, s8 = task & 7;
      short8 o;
#pragma unroll
      for (int i = 0; i < 8; i++) o[i] = Cs[(s8 * 8 + i) * 72 + fl];
      int hh = hv0 + (fl >> 5), d = fl & 31;
      *reinterpret_cast<short8*>(&VaT[((size_t)(b * 8 + hh) * 48 + d) * S_ + sbase + s8 * 8]) = o;
    }
  }
}

// ---------------- flash attention: swapped QK^T, register P, K=16 PV ----------------
// grid: (S/64, H, B*2); block 256 = 4 waves, each wave 16 queries.
// LDS layout in smem: Kb0 @0 (9216B), Kb1 @9216, Vb0 @18432 (6912B), Vb1 @25344,
// msk @32256 (512B). Epilogue overlays Of (64x52 f32) at 0.

__global__ __launch_bounds__(256, 4) void attn(
    const short* __restrict__ Qa, const short* __restrict__ Ka,
    const short* __restrict__ VaT, const int* __restrict__ mask,
    float* __restrict__ AccO, float* __restrict__ AccL) {
  __shared__ __align__(16) char smem[32768];

  int it = blockIdx.x, h = blockIdx.y, bz = blockIdx.z;
  int b = bz >> 1, split = bz & 1;
  int tid = threadIdx.x, lane = tid & 63, w = tid >> 6;
  int t = lane & 15, g = lane >> 4, kf = g * 8;
  int q0w = it * 64 + w * 16;
  int bhv = b * H_ + h;
  size_t bh = (size_t)bhv * S_;

  short8 aq0 = *reinterpret_cast<const short8*>(&Qa[(bh + q0w + t) * AUGQ + kf]);
  short8 aq1 = *reinterpret_cast<const short8*>(&Qa[(bh + q0w + t) * AUGQ + 32 + kf]);

  f32x4 Oacc[3] = {};
  float lsum = 0.f;

  uint4 kreg0, kreg1, vreg0, vreg1;
  float mreg = 0.f;
  int srow = tid >> 3, sko = (tid & 7) * 8;
  const int jt0 = split * NJ;

  auto issue = [&](int jt) {
    const uint4* ks = reinterpret_cast<const uint4*>(&Ka[(bh + jt * 64) * AUGQ]);
    kreg0 = ks[tid];
    kreg1 = ks[tid + 256];
    size_t vb = (size_t)bhv * 48 * S_ + jt * 64;
    vreg0 = *reinterpret_cast<const uint4*>(&VaT[vb + (size_t)srow * S_ + sko]);
    if (tid < 128)
      vreg1 = *reinterpret_cast<const uint4*>(&VaT[vb + (size_t)(srow + 32) * S_ + sko]);
    if (tid < 64) mreg = mask[b * S_ + jt * 64 + tid] ? 0.f : -1e9f;
  };
  auto commit = [&](int buf) {
    short* Kd = (short*)(smem + buf * 9216);
    short* Vd = (short*)(smem + 18432 + buf * 6912);
    float* md = (float*)(smem + 32256);
    *reinterpret_cast<uint4*>(&Kd[srow * KPAD + sko]) = kreg0;
    *reinterpret_cast<uint4*>(&Kd[(srow + 32) * KPAD + sko]) = kreg1;
    *reinterpret_cast<uint4*>(&Vd[srow * KPAD + sko]) = vreg0;
    if (tid < 128)
      *reinterpret_cast<uint4*>(&Vd[(srow + 32) * KPAD + sko]) = vreg1;
    if (tid < 64) md[buf * 64 + tid] = mreg;
  };

  issue(jt0);
  commit(0);
  __syncthreads();

  for (int j = 0; j < NJ; j++) {
    int cur = j & 1;
    if (j + 1 < NJ) issue(jt0 + j + 1);
    const short* Kc = (const short*)(smem + cur * 9216);
    const short* Vc = (const short*)(smem + 18432 + cur * 6912);
    const float* mc = (const float*)(smem + 32256) + cur * 64;
    short4v pb[4];
#pragma unroll
    for (int sub = 0; sub < 4; sub++) {
      short8 ka0 = *reinterpret_cast<const short8*>(&Kc[(sub * 16 + t) * KPAD + kf]);
      short8 ka1 = *reinterpret_cast<const short8*>(&Kc[(sub * 16 + t) * KPAD + 32 + kf]);
      f32x4 s0 = {};
      s0 = __builtin_amdgcn_mfma_f32_16x16x32_bf16(ka0, aq0, s0, 0, 0, 0);
      s0 = __builtin_amdgcn_mfma_f32_16x16x32_bf16(ka1, aq1, s0, 0, 0, 0);
      f32x4 m4 = *reinterpret_cast<const f32x4*>(&mc[sub * 16 + g * 4]);
      float p0 = __expf(s0[0] + m4[0]);
      float p1 = __expf(s0[1] + m4[1]);
      float p2 = __expf(s0[2] + m4[2]);
      float p3 = __expf(s0[3] + m4[3]);
      lsum += (p0 + p1) + (p2 + p3);
      short4v pk4;
      pk4[0] = bf16_of(p0); pk4[1] = bf16_of(p1);
      pk4[2] = bf16_of(p2); pk4[3] = bf16_of(p3);
      pb[sub] = pk4;
    }
#pragma unroll
    for (int tt = 0; tt < 3; tt++) {
#pragma unroll
      for (int sub = 0; sub < 4; sub++) {
        short4v va = *reinterpret_cast<const short4v*>(&Vc[(tt * 16 + t) * KPAD + sub * 16 + g * 4]);
        Oacc[tt] = mfma16(va, pb[sub], Oacc[tt]);
      }
    }
    if (j + 1 < NJ) commit(cur ^ 1);
    __syncthreads();
  }

  // epilogue: reduce lsum across g-groups; transpose O via LDS; contiguous f32x4 out
  lsum += __shfl_xor(lsum, 16);
  lsum += __shfl_xor(lsum, 32);

  float* Of = (float*)smem;  // 64 x 52 f32 overlay
  size_t obase = ((size_t)(split * NBH + bhv)) * S_;
#pragma unroll
  for (int tt = 0; tt < 3; tt++)
#pragma unroll
    for (int r = 0; r < 4; r++)
      Of[(w * 16 + t) * 52 + tt * 16 + g * 4 + r] = Oacc[tt][r];
  if (lane < 16) AccL[obase + q0w + lane] = lsum;
  __syncthreads();
  int row = tid >> 2, q4 = tid & 3;
#pragma unroll
  for (int k2 = 0; k2 < 3; k2++) {
    *reinterpret_cast<f32x4*>(&AccO[(obase + it * 64 + row) * 48 + q4 * 12 + k2 * 4]) =
        *reinterpret_cast<const f32x4*>(&Of[row * 52 + q4 * 12 + k2 * 4]);
  }
}

// ---------------- output projection with fused split-merge ----------------
// grid (64, 4), 512 threads (8 waves)

__global__ __launch_bounds__(512) void out_gemm(
    const float* __restrict__ AccO, const float* __restrict__ AccL,
    const short* __restrict__ Wot, const float* __restrict__ bo,
    float* __restrict__ Out) {
  __shared__ __align__(16) short As[64 * 136];
  __shared__ __align__(16) short Bs[64 * 136];
  int m0 = blockIdx.x * 64, n0 = blockIdx.y * 64;
  int tid = threadIdx.x, lane = tid & 63, w = tid >> 6;
  int t = lane & 15, g = lane >> 4, kf = g * 8;
  int wm = w & 3, wn = w >> 2;
  int b = m0 >> 11, sbase = m0 & 2047;
  f32x4 acc[2] = {};
  int srow = tid >> 3, skc = (tid & 7) * 16;
  for (int ph = 0; ph < 2; ph++) {
    int k0 = ph * 128;
    __syncthreads();
    {
      int kg = k0 + skc;
      int hh = kg >> 5, d0 = kg & 31;
      size_t rowO = (size_t)(b * 8 + hh) * S_ + sbase + srow;
      float l = AccL[rowO] + AccL[rowO + (size_t)NBH * S_];
      float inv = 1.0f / l;
      size_t r0 = rowO * 48 + d0;
      size_t r1 = (rowO + (size_t)NBH * S_) * 48 + d0;
#pragma unroll
      for (int i = 0; i < 4; i++) {
        f32x4 a0 = *reinterpret_cast<const f32x4*>(&AccO[r0 + i * 4]);
        f32x4 a1 = *reinterpret_cast<const f32x4*>(&AccO[r1 + i * 4]);
        short4v o;
#pragma unroll
        for (int c = 0; c < 4; c++) o[c] = bf16_of((a0[c] + a1[c]) * inv);
        *reinterpret_cast<short4v*>(&As[srow * 136 + skc + i * 4]) = o;
      }
      *reinterpret_cast<uint4*>(&Bs[srow * 136 + skc]) =
          *reinterpret_cast<const uint4*>(&Wot[(size_t)(n0 + srow) * 256 + kg]);
      *reinterpret_cast<uint4*>(&Bs[srow * 136 + skc + 8]) =
          *reinterpret_cast<const uint4*>(&Wot[(size_t)(n0 + srow) * 256 + kg + 8]);
    }
    __syncthreads();
#pragma unroll
    for (int kk = 0; kk < 4; kk++) {
      short8 a = *reinterpret_cast<const short8*>(&As[(wm * 16 + t) * 136 + kk * 32 + kf]);
#pragma unroll
      for (int jj = 0; jj < 2; jj++) {
        short8 bb = *reinterpret_cast<const short8*>(&Bs[(wn * 32 + jj * 16 + t) * 136 + kk * 32 + kf]);
        acc[jj] = __builtin_amdgcn_mfma_f32_16x16x32_bf16(a, bb, acc[jj], 0, 0, 0);
      }
    }
  }
#pragma unroll
  for (int jj = 0; jj < 2; jj++)
#pragma unroll
    for (int r = 0; r < 4; r++) {
      int mrow = m0 + wm * 16 + g * 4 + r;
      int n = n0 + wn * 32 + jj * 16 + t;
      Out[(size_t)mrow * 256 + n] = acc[jj][r] + bo[n];
    }
}

// ---------------- point projection with fused split-merge ----------------
// 4 threads per output row; grid 64 x 256

__global__ void point_proj(const float* __restrict__ AccO, const float* __restrict__ AccL,
                           const float* __restrict__ Wpo, const float* __restrict__ bpo,
                           float* __restrict__ out) {
  int gid = blockIdx.x * 256 + threadIdx.x;
  int m = gid >> 2, qr = gid & 3;
  int b = m >> 11, s = m & 2047;
  float a0 = 0.f, a1 = 0.f, a2 = 0.f;
#pragma unroll
  for (int h2 = 0; h2 < 2; h2++) {
    int hh = qr * 2 + h2;
    size_t rowO = (size_t)(b * 8 + hh) * S_ + s;
    float inv = 1.0f / (AccL[rowO] + AccL[rowO + (size_t)NBH * S_]);
    size_t r0 = rowO * 48 + 32;
    size_t r1 = (rowO + (size_t)NBH * S_) * 48 + 32;
#pragma unroll
    for (int i = 0; i < 4; i++) {
      f32x4 v0 = *reinterpret_cast<const f32x4*>(&AccO[r0 + i * 4]);
      f32x4 v1 = *reinterpret_cast<const f32x4*>(&AccO[r1 + i * 4]);
#pragma unroll
      for (int c = 0; c < 4; c++) {
        float val = (v0[c] + v1[c]) * inv;
        int j = hh * 16 + i * 4 + c;
        a0 += val * Wpo[j * 3 + 0];
        a1 += val * Wpo[j * 3 + 1];
        a2 += val * Wpo[j * 3 + 2];
      }
    }
  }
  a0 += __shfl_xor(a0, 1); a0 += __shfl_xor(a0, 2);
  a1 += __shfl_xor(a1, 1); a1 += __shfl_xor(a1, 2);
  a2 += __shfl_xor(a2, 1); a2 += __shfl_xor(a2, 2);
  if (qr == 0) {
    out[(size_t)m * 3 + 0] = a0 + bpo[0];
    out[(size_t)m * 3 + 1] = a1 + bpo[1];
    out[(size_t)m * 3 + 2] = a2 + bpo[2];
  }
}

// ---------------- launch ----------------

extern "C" void kernel_launch(void* const* d_in, const int* in_sizes, int n_in,
                              void* d_out, int out_size, void* d_ws, size_t ws_size,
                              hipStream_t stream) {
  const float* seq    = (const float*)d_in[0];
  const float* coords = (const float*)d_in[1];
  const int*   mask   = (const int*)d_in[3];
  const float* Wq  = (const float*)d_in[4];
  const float* bq  = (const float*)d_in[5];
  const float* Wk  = (const float*)d_in[6];
  const float* bk  = (const float*)d_in[7];
  const float* Wv  = (const float*)d_in[8];
  const float* bv  = (const float*)d_in[9];
  const float* Wpq = (const float*)d_in[10];
  const float* bpq = (const float*)d_in[11];
  const float* Wpk = (const float*)d_in[12];
  const float* bpk = (const float*)d_in[13];
  const float* Wo  = (const float*)d_in[14];
  const float* bo  = (const float*)d_in[15];
  const float* Wpo = (const float*)d_in[16];
  const float* bpo = (const float*)d_in[17];
  float* out = (float*)d_out;

  char* ws = (char*)d_ws;
  short* Wqkv_t = (short*)ws; ws += 768 * 256 * 2;
  short* Wo_t   = (short*)ws; ws += 256 * 256 * 2;
  short* Qa     = (short*)ws; ws += (size_t)NBH * S_ * AUGQ * 2;
  short* Ka     = (short*)ws; ws += (size_t)NBH * S_ * AUGQ * 2;
  short* VaT    = (short*)ws; ws += (size_t)NBH * 48 * S_ * 2;
  float* AccO   = (float*)ws; ws += (size_t)2 * NBH * S_ * 48 * 4;
  float* AccL   = (float*)ws; ws += (size_t)2 * NBH * S_ * 4;

  prep_all<<<1024, 256, 0, stream>>>(Wq, Wk, Wv, Wo, coords, Wpq, bpq, Wpk, bpk,
                                     Wqkv_t, Wo_t, Qa, Ka, VaT);
  qkv_gemm<<<dim3(64, 12), 256, 0, stream>>>(seq, Wqkv_t, bq, bk, bv, Qa, Ka, VaT);
  attn<<<dim3(32, 8, 4), 256, 0, stream>>>(Qa, Ka, VaT, mask, AccO, AccL);
  out_gemm<<<dim3(64, 4), 512, 0, stream>>>(AccO, AccL, Wo_t, bo, out);
  point_proj<<<64, 256, 0, stream>>>(AccO, AccL, Wpo, bpo, out + (size_t)MTOT * 256);
}

// Round 5
// 69.375 us; speedup vs baseline: 2.0790x; 1.0230x over previous
//
#include <hip/hip_runtime.h>
#include <hip/hip_bf16.h>

#define D_ 256
#define H_ 8
#define B_ 2
#define S_ 2048
#define MTOT 4096
#define AUGQ 64          // q(32) + pq(16) + [maskbias/1.0](1) + pad(15)
#define NBH 16           // B_*H_
#define KPAD 72
#define NJ 16            // key tiles (of 64) per split

typedef __attribute__((ext_vector_type(8))) short short8;
typedef __attribute__((ext_vector_type(4))) short short4v;
typedef __attribute__((ext_vector_type(4))) float f32x4;

static __device__ __forceinline__ short bf16_of(float f) {
  union { __hip_bfloat16 h; short s; } u;
  u.h = __float2bfloat16(f);
  return u.s;
}
static __device__ __forceinline__ float f_of_bf16(short s) {
  union { float f; unsigned int u; } u;
  u.u = ((unsigned int)(unsigned short)s) << 16;
  return u.f;
}

static __device__ __forceinline__ f32x4 mfma16(short4v a, short4v b, f32x4 c) {
#if defined(__has_builtin) && __has_builtin(__builtin_amdgcn_mfma_f32_16x16x16bf16_1k)
  return __builtin_amdgcn_mfma_f32_16x16x16bf16_1k(a, b, c, 0, 0, 0);
#else
  asm("v_mfma_f32_16x16x16_bf16 %0, %1, %2, %0" : "+v"(c) : "v"(a), "v"(b));
  return c;
#endif
}

// ---------------- fused prep: weights cvt/transpose + pq/pk fills ----------------

__global__ void prep_all(const float* __restrict__ Wq, const float* __restrict__ Wk,
                         const float* __restrict__ Wv, const float* __restrict__ Wo,
                         const float* __restrict__ coords, const int* __restrict__ mask,
                         const float* __restrict__ Wpq, const float* __restrict__ bpq,
                         const float* __restrict__ Wpk, const float* __restrict__ bpk,
                         short* __restrict__ Wqkv_t, short* __restrict__ Wo_t,
                         short* __restrict__ Qa, short* __restrict__ Ka,
                         short* __restrict__ VaT) {
  int gid = blockIdx.x * 256 + threadIdx.x;
  int NT = gridDim.x * 256;
  for (int idx = gid; idx < 768 * 256; idx += NT) {
    int n = idx >> 8, k = idx & 255;
    const float* W = (n < 256) ? Wq : (n < 512 ? Wk : Wv);
    Wqkv_t[idx] = bf16_of(W[k * 256 + (n & 255)]);
  }
  for (int idx = gid; idx < 256 * 256; idx += NT) {
    int n = idx >> 8, k = idx & 255;
    Wo_t[idx] = bf16_of(Wo[k * 256 + n]);
  }
  // pq/pk augmented cols, vectorized: one thread per (m, h)
  for (int idx = gid; idx < MTOT * 8; idx += NT) {
    int m = idx >> 3, h = idx & 7;
    int b = m >> 11, s = m & 2047;
    float r0 = coords[m * 9 + 3], r1 = coords[m * 9 + 4], r2 = coords[m * 9 + 5];
    size_t base = ((size_t)(b * 8 + h) * S_ + s) * AUGQ;
    short8 pqv[2], pkv[2];
#pragma unroll
    for (int c = 0; c < 2; c++)
#pragma unroll
      for (int i = 0; i < 8; i++) {
        int j = h * 16 + c * 8 + i;
        float pq = r0 * Wpq[j] + r1 * Wpq[128 + j] + r2 * Wpq[256 + j] + bpq[j];
        float pk = r0 * Wpk[j] + r1 * Wpk[128 + j] + r2 * Wpk[256 + j] + bpk[j];
        pqv[c][i] = bf16_of(pq);
        pkv[c][i] = bf16_of(pk * 0.25f);
      }
    short8 padq = {};
    padq[0] = 0x3F80;  // bf16(1.0) -> multiplies Ka's mask-bias col
    short8 padk = {};
    padk[0] = mask[m] ? (short)0 : bf16_of(-1e9f);
    short8 z = {};
    *reinterpret_cast<short8*>(&Qa[base + 32]) = pqv[0];
    *reinterpret_cast<short8*>(&Qa[base + 40]) = pqv[1];
    *reinterpret_cast<short8*>(&Qa[base + 48]) = padq;
    *reinterpret_cast<short8*>(&Qa[base + 56]) = z;
    *reinterpret_cast<short8*>(&Ka[base + 32]) = pkv[0];
    *reinterpret_cast<short8*>(&Ka[base + 40]) = pkv[1];
    *reinterpret_cast<short8*>(&Ka[base + 48]) = padk;
    *reinterpret_cast<short8*>(&Ka[base + 56]) = z;
  }
  // pq into VaT (transposed layout [bh][32+p][s])
  for (int idx = gid; idx < NBH * 16 * (S_ / 8); idx += NT) {
    int s8 = idx & 255, p = (idx >> 8) & 15, bh = idx >> 12;
    int b = bh >> 3, h = bh & 7, j = h * 16 + p;
    float w0 = Wpq[j], w1 = Wpq[128 + j], w2 = Wpq[256 + j], bb = bpq[j];
    short8 o;
#pragma unroll
    for (int i = 0; i < 8; i++) {
      int m = b * 2048 + s8 * 8 + i;
      o[i] = bf16_of(coords[m * 9 + 3] * w0 + coords[m * 9 + 4] * w1 +
                     coords[m * 9 + 5] * w2 + bb);
    }
    *reinterpret_cast<short8*>(&VaT[((size_t)bh * 48 + 32 + p) * S_ + s8 * 8]) = o;
  }
}

// ---------------- QKV GEMM (M=4096, N=768, K=256), f32 input, vector epilogue ----------------

__global__ __launch_bounds__(256) void qkv_gemm(
    const float* __restrict__ X, const short* __restrict__ Wt,
    const float* __restrict__ bq, const float* __restrict__ bk, const float* __restrict__ bv,
    short* __restrict__ Qa, short* __restrict__ Ka, short* __restrict__ VaT) {
  __shared__ __align__(16) short As[64 * 136];
  __shared__ __align__(16) short Bs[64 * 136];
  int m0 = blockIdx.x * 64, n0 = blockIdx.y * 64;
  int tid = threadIdx.x, lane = tid & 63, w = tid >> 6;
  int t = lane & 15, g = lane >> 4, kf = g * 8;
  int wr = (w >> 1) * 32, wc = (w & 1) * 32;
  f32x4 acc[2][2] = {};
  int srow = tid >> 2, skc = (tid & 3) * 32;
  for (int ph = 0; ph < 2; ph++) {
    int k0 = ph * 128;
    __syncthreads();
    {
      const float* xs = &X[(size_t)(m0 + srow) * 256 + k0 + skc];
      short4v av[8];
#pragma unroll
      for (int i = 0; i < 8; i++) {
        f32x4 xv = *reinterpret_cast<const f32x4*>(&xs[i * 4]);
        short4v o;
        o[0] = bf16_of(xv[0]); o[1] = bf16_of(xv[1]);
        o[2] = bf16_of(xv[2]); o[3] = bf16_of(xv[3]);
        av[i] = o;
      }
#pragma unroll
      for (int i = 0; i < 8; i++)
        *reinterpret_cast<short4v*>(&As[srow * 136 + skc + i * 4]) = av[i];
      const uint4* wsrc = reinterpret_cast<const uint4*>(&Wt[(size_t)(n0 + srow) * 256 + k0 + skc]);
#pragma unroll
      for (int i = 0; i < 4; i++)
        *reinterpret_cast<uint4*>(&Bs[srow * 136 + skc + i * 8]) = wsrc[i];
    }
    __syncthreads();
#pragma unroll
    for (int kk = 0; kk < 4; kk++) {
      short8 a[2], bb[2];
#pragma unroll
      for (int i = 0; i < 2; i++)
        a[i] = *reinterpret_cast<const short8*>(&As[(wr + i * 16 + t) * 136 + kk * 32 + kf]);
#pragma unroll
      for (int jj = 0; jj < 2; jj++)
        bb[jj] = *reinterpret_cast<const short8*>(&Bs[(wc + jj * 16 + t) * 136 + kk * 32 + kf]);
#pragma unroll
      for (int i = 0; i < 2; i++)
#pragma unroll
        for (int jj = 0; jj < 2; jj++)
          acc[i][jj] = __builtin_amdgcn_mfma_f32_16x16x32_bf16(a[i], bb[jj], acc[i][jj], 0, 0, 0);
    }
  }
  // epilogue: bias/scale -> LDS bf16 tile -> vector stores
  __syncthreads();
  short* Cs = As;
  const float scale = 0.17677669529663687f;  // 1/sqrt(32)
  int b = m0 >> 11, sbase = m0 & 2047;
#pragma unroll
  for (int i = 0; i < 2; i++)
#pragma unroll
    for (int jj = 0; jj < 2; jj++)
#pragma unroll
      for (int r = 0; r < 4; r++) {
        int rl = wr + i * 16 + g * 4 + r;
        int cl = wc + jj * 16 + t;
        int n = n0 + cl;
        float v = acc[i][jj][r];
        if (n < 256) v = (v + bq[n]) * scale;
        else if (n < 512) v = v + bk[n - 256];
        else v = v + bv[n - 512];
        Cs[rl * 72 + cl] = bf16_of(v);
      }
  __syncthreads();
  if (n0 < 512) {
#pragma unroll
    for (int i2 = 0; i2 < 2; i2++) {
      int task = tid + i2 * 256;
      int row = task >> 3, c = task & 7;
      int n = n0 + c * 8;
      short* dst = (n < 256) ? Qa : Ka;
      int nn = n & 255;
      int hh = nn >> 5, d = nn & 31;
      *reinterpret_cast<short8*>(&dst[((size_t)(b * 8 + hh) * S_ + sbase + row) * AUGQ + d]) =
          *reinterpret_cast<const short8*>(&Cs[row * 72 + c * 8]);
    }
  } else {
    int hv0 = (n0 - 512) >> 5;
#pragma unroll
    for (int i2 = 0; i2 < 2; i2++) {
      int task = tid + i2 * 256;
      int fl = task >> 3, s8 = task & 7;
      short8 o;
#pragma unroll
      for (int i = 0; i < 8; i++) o[i] = Cs[(s8 * 8 + i) * 72 + fl];
      int hh = hv0 + (fl >> 5), d = fl & 31;
      *reinterpret_cast<short8*>(&VaT[((size_t)(b * 8 + hh) * 48 + d) * S_ + sbase + s8 * 8]) = o;
    }
  }
}

// ---------------- flash attention: swapped QK^T, register P, K=16 PV ----------------
// 1-D grid 1024, XCD-swizzled; block 256 = 4 waves, each wave 16 queries.
// LDS: Kb0 @0 (9216B), Kb1 @9216, Vb0 @18432 (6912B), Vb1 @25344. Total 32256.
// Epilogue overlays Of (64x52 f32) at 0.

__global__ __launch_bounds__(256, 4) void attn(
    const short* __restrict__ Qa, const short* __restrict__ Ka,
    const short* __restrict__ VaT,
    short* __restrict__ Ctx0, short* __restrict__ Ctx1,
    float* __restrict__ AccL) {
  __shared__ __align__(16) char smem[32256];

  // XCD-aware decode: xcd = bid&7 owns 4 (bh,split) KV streams (L2-resident)
  int bid = blockIdx.x;
  int xcd = bid & 7, slot = bid >> 3;       // slot 0..127
  int gidx = xcd * 4 + (slot >> 5);         // 0..31 = bh*2+split
  int it = slot & 31;
  int split = gidx & 1;
  int bhv = gidx >> 1;

  int tid = threadIdx.x, lane = tid & 63, w = tid >> 6;
  int t = lane & 15, g = lane >> 4, kf = g * 8;
  int q0w = it * 64 + w * 16;
  size_t bh = (size_t)bhv * S_;

  short8 aq0 = *reinterpret_cast<const short8*>(&Qa[(bh + q0w + t) * AUGQ + kf]);
  short8 aq1 = *reinterpret_cast<const short8*>(&Qa[(bh + q0w + t) * AUGQ + 32 + kf]);

  f32x4 Oacc[3] = {};
  float lsum = 0.f;

  uint4 kreg0, kreg1, vreg0, vreg1;
  int srow = tid >> 3, sko = (tid & 7) * 8;
  const int jt0 = split * NJ;

  auto issue = [&](int jt) {
    const uint4* ks = reinterpret_cast<const uint4*>(&Ka[(bh + jt * 64) * AUGQ]);
    kreg0 = ks[tid];
    kreg1 = ks[tid + 256];
    size_t vb = (size_t)bhv * 48 * S_ + jt * 64;
    vreg0 = *reinterpret_cast<const uint4*>(&VaT[vb + (size_t)srow * S_ + sko]);
    if (tid < 128)
      vreg1 = *reinterpret_cast<const uint4*>(&VaT[vb + (size_t)(srow + 32) * S_ + sko]);
  };
  auto commit = [&](int buf) {
    short* Kd = (short*)(smem + buf * 9216);
    short* Vd = (short*)(smem + 18432 + buf * 6912);
    *reinterpret_cast<uint4*>(&Kd[srow * KPAD + sko]) = kreg0;
    *reinterpret_cast<uint4*>(&Kd[(srow + 32) * KPAD + sko]) = kreg1;
    *reinterpret_cast<uint4*>(&Vd[srow * KPAD + sko]) = vreg0;
    if (tid < 128)
      *reinterpret_cast<uint4*>(&Vd[(srow + 32) * KPAD + sko]) = vreg1;
  };

  issue(jt0);
  commit(0);
  __syncthreads();

  for (int j = 0; j < NJ; j++) {
    int cur = j & 1;
    if (j + 1 < NJ) issue(jt0 + j + 1);
    const short* Kc = (const short*)(smem + cur * 9216);
    const short* Vc = (const short*)(smem + 18432 + cur * 6912);
    short4v pb[4];
#pragma unroll
    for (int sub = 0; sub < 4; sub++) {
      short8 ka0 = *reinterpret_cast<const short8*>(&Kc[(sub * 16 + t) * KPAD + kf]);
      short8 ka1 = *reinterpret_cast<const short8*>(&Kc[(sub * 16 + t) * KPAD + 32 + kf]);
      f32x4 s0 = {};
      s0 = __builtin_amdgcn_mfma_f32_16x16x32_bf16(ka0, aq0, s0, 0, 0, 0);
      s0 = __builtin_amdgcn_mfma_f32_16x16x32_bf16(ka1, aq1, s0, 0, 0, 0);
      float p0 = __expf(s0[0]);
      float p1 = __expf(s0[1]);
      float p2 = __expf(s0[2]);
      float p3 = __expf(s0[3]);
      lsum += (p0 + p1) + (p2 + p3);
      short4v pk4;
      pk4[0] = bf16_of(p0); pk4[1] = bf16_of(p1);
      pk4[2] = bf16_of(p2); pk4[3] = bf16_of(p3);
      pb[sub] = pk4;
    }
#pragma unroll
    for (int tt = 0; tt < 3; tt++) {
#pragma unroll
      for (int sub = 0; sub < 4; sub++) {
        short4v va = *reinterpret_cast<const short4v*>(&Vc[(tt * 16 + t) * KPAD + sub * 16 + g * 4]);
        Oacc[tt] = mfma16(va, pb[sub], Oacc[tt]);
      }
    }
    if (j + 1 < NJ) commit(cur ^ 1);
    __syncthreads();
  }

  // epilogue: reduce lsum across g-groups; transpose O via LDS; bf16 partial ctx out
  lsum += __shfl_xor(lsum, 16);
  lsum += __shfl_xor(lsum, 32);

  float* Of = (float*)smem;  // 64 x 52 f32 overlay
#pragma unroll
  for (int tt = 0; tt < 3; tt++)
#pragma unroll
    for (int r = 0; r < 4; r++)
      Of[(w * 16 + t) * 52 + tt * 16 + g * 4 + r] = Oacc[tt][r];
  if (lane < 16) AccL[(size_t)(split * NBH + bhv) * S_ + q0w + lane] = lsum;
  __syncthreads();
  short* CtxP = split ? Ctx1 : Ctx0;
  size_t obase = bh + it * 64;
  for (int task = tid; task < 384; task += 256) {
    int row = task / 6, c8 = task % 6;
    const float* src = &Of[row * 52 + c8 * 8];
    short8 o;
#pragma unroll
    for (int i = 0; i < 8; i++) o[i] = bf16_of(src[i]);
    *reinterpret_cast<short8*>(&CtxP[(obase + row) * 48 + c8 * 8]) = o;
  }
}

// ---------------- output projection with fused bf16 split-merge ----------------
// grid (64, 4), 512 threads (8 waves)

__global__ __launch_bounds__(512) void out_gemm(
    const short* __restrict__ Ctx0, const short* __restrict__ Ctx1,
    const float* __restrict__ AccL,
    const short* __restrict__ Wot, const float* __restrict__ bo,
    float* __restrict__ Out) {
  __shared__ __align__(16) short As[64 * 136];
  __shared__ __align__(16) short Bs[64 * 136];
  int m0 = blockIdx.x * 64, n0 = blockIdx.y * 64;
  int tid = threadIdx.x, lane = tid & 63, w = tid >> 6;
  int t = lane & 15, g = lane >> 4, kf = g * 8;
  int wm = w & 3, wn = w >> 2;
  int b = m0 >> 11, sbase = m0 & 2047;
  f32x4 acc[2] = {};
  int srow = tid >> 3, skc = (tid & 7) * 16;
  for (int ph = 0; ph < 2; ph++) {
    int k0 = ph * 128;
    __syncthreads();
    {
      int kg = k0 + skc;
      int hh = kg >> 5, d0 = kg & 31;
      size_t rowO = (size_t)(b * 8 + hh) * S_ + sbase + srow;
      float inv = 1.0f / (AccL[rowO] + AccL[rowO + (size_t)NBH * S_]);
      const short8* c0 = reinterpret_cast<const short8*>(&Ctx0[rowO * 48 + d0]);
      const short8* c1 = reinterpret_cast<const short8*>(&Ctx1[rowO * 48 + d0]);
#pragma unroll
      for (int half = 0; half < 2; half++) {
        short8 a0 = c0[half], a1 = c1[half];
        short8 o;
#pragma unroll
        for (int c = 0; c < 8; c++)
          o[c] = bf16_of((f_of_bf16(a0[c]) + f_of_bf16(a1[c])) * inv);
        *reinterpret_cast<short8*>(&As[srow * 136 + skc + half * 8]) = o;
      }
      *reinterpret_cast<uint4*>(&Bs[srow * 136 + skc]) =
          *reinterpret_cast<const uint4*>(&Wot[(size_t)(n0 + srow) * 256 + kg]);
      *reinterpret_cast<uint4*>(&Bs[srow * 136 + skc + 8]) =
          *reinterpret_cast<const uint4*>(&Wot[(size_t)(n0 + srow) * 256 + kg + 8]);
    }
    __syncthreads();
#pragma unroll
    for (int kk = 0; kk < 4; kk++) {
      short8 a = *reinterpret_cast<const short8*>(&As[(wm * 16 + t) * 136 + kk * 32 + kf]);
#pragma unroll
      for (int jj = 0; jj < 2; jj++) {
        short8 bb = *reinterpret_cast<const short8*>(&Bs[(wn * 32 + jj * 16 + t) * 136 + kk * 32 + kf]);
        acc[jj] = __builtin_amdgcn_mfma_f32_16x16x32_bf16(a, bb, acc[jj], 0, 0, 0);
      }
    }
  }
#pragma unroll
  for (int jj = 0; jj < 2; jj++)
#pragma unroll
    for (int r = 0; r < 4; r++) {
      int mrow = m0 + wm * 16 + g * 4 + r;
      int n = n0 + wn * 32 + jj * 16 + t;
      Out[(size_t)mrow * 256 + n] = acc[jj][r] + bo[n];
    }
}

// ---------------- point projection with fused bf16 split-merge ----------------
// 4 threads per output row; grid 64 x 256

__global__ void point_proj(const short* __restrict__ Ctx0, const short* __restrict__ Ctx1,
                           const float* __restrict__ AccL,
                           const float* __restrict__ Wpo, const float* __restrict__ bpo,
                           float* __restrict__ out) {
  int gid = blockIdx.x * 256 + threadIdx.x;
  int m = gid >> 2, qr = gid & 3;
  int b = m >> 11, s = m & 2047;
  float a0 = 0.f, a1 = 0.f, a2 = 0.f;
#pragma unroll
  for (int h2 = 0; h2 < 2; h2++) {
    int hh = qr * 2 + h2;
    size_t rowO = (size_t)(b * 8 + hh) * S_ + s;
    float inv = 1.0f / (AccL[rowO] + AccL[rowO + (size_t)NBH * S_]);
    const short8* c0 = reinterpret_cast<const short8*>(&Ctx0[rowO * 48 + 32]);
    const short8* c1 = reinterpret_cast<const short8*>(&Ctx1[rowO * 48 + 32]);
#pragma unroll
    for (int half = 0; half < 2; half++) {
      short8 v0 = c0[half], v1 = c1[half];
#pragma unroll
      for (int c = 0; c < 8; c++) {
        float val = (f_of_bf16(v0[c]) + f_of_bf16(v1[c])) * inv;
        int j = hh * 16 + half * 8 + c;
        a0 += val * Wpo[j * 3 + 0];
        a1 += val * Wpo[j * 3 + 1];
        a2 += val * Wpo[j * 3 + 2];
      }
    }
  }
  a0 += __shfl_xor(a0, 1); a0 += __shfl_xor(a0, 2);
  a1 += __shfl_xor(a1, 1); a1 += __shfl_xor(a1, 2);
  a2 += __shfl_xor(a2, 1); a2 += __shfl_xor(a2, 2);
  if (qr == 0) {
    out[(size_t)m * 3 + 0] = a0 + bpo[0];
    out[(size_t)m * 3 + 1] = a1 + bpo[1];
    out[(size_t)m * 3 + 2] = a2 + bpo[2];
  }
}

// ---------------- launch ----------------

extern "C" void kernel_launch(void* const* d_in, const int* in_sizes, int n_in,
                              void* d_out, int out_size, void* d_ws, size_t ws_size,
                              hipStream_t stream) {
  const float* seq    = (const float*)d_in[0];
  const float* coords = (const float*)d_in[1];
  const int*   mask   = (const int*)d_in[3];
  const float* Wq  = (const float*)d_in[4];
  const float* bq  = (const float*)d_in[5];
  const float* Wk  = (const float*)d_in[6];
  const float* bk  = (const float*)d_in[7];
  const float* Wv  = (const float*)d_in[8];
  const float* bv  = (const float*)d_in[9];
  const float* Wpq = (const float*)d_in[10];
  const float* bpq = (const float*)d_in[11];
  const float* Wpk = (const float*)d_in[12];
  const float* bpk = (const float*)d_in[13];
  const float* Wo  = (const float*)d_in[14];
  const float* bo  = (const float*)d_in[15];
  const float* Wpo = (const float*)d_in[16];
  const float* bpo = (const float*)d_in[17];
  float* out = (float*)d_out;

  char* ws = (char*)d_ws;
  short* Wqkv_t = (short*)ws; ws += 768 * 256 * 2;
  short* Wo_t   = (short*)ws; ws += 256 * 256 * 2;
  short* Qa     = (short*)ws; ws += (size_t)NBH * S_ * AUGQ * 2;
  short* Ka     = (short*)ws; ws += (size_t)NBH * S_ * AUGQ * 2;
  short* VaT    = (short*)ws; ws += (size_t)NBH * 48 * S_ * 2;
  short* Ctx0   = (short*)ws; ws += (size_t)NBH * S_ * 48 * 2;
  short* Ctx1   = (short*)ws; ws += (size_t)NBH * S_ * 48 * 2;
  float* AccL   = (float*)ws; ws += (size_t)2 * NBH * S_ * 4;

  prep_all<<<1024, 256, 0, stream>>>(Wq, Wk, Wv, Wo, coords, mask, Wpq, bpq, Wpk, bpk,
                                     Wqkv_t, Wo_t, Qa, Ka, VaT);
  qkv_gemm<<<dim3(64, 12), 256, 0, stream>>>(seq, Wqkv_t, bq, bk, bv, Qa, Ka, VaT);
  attn<<<1024, 256, 0, stream>>>(Qa, Ka, VaT, Ctx0, Ctx1, AccL);
  out_gemm<<<dim3(64, 4), 512, 0, stream>>>(Ctx0, Ctx1, AccL, Wo_t, bo, out);
  point_proj<<<64, 256, 0, stream>>>(Ctx0, Ctx1, AccL, Wpo, bpo, out + (size_t)MTOT * 256);
}